// Round 10
// baseline (486.980 us; speedup 1.0000x reference)
//
#include <hip/hip_runtime.h>
#include <hip/hip_bf16.h>

// Single-head causal attention, B=16, T=2048, D=H=1024.
// cvt x->f16 (d_out lo) | transpose W | fused QK GEMM (Q->ws, K->d_out hi) |
// Vt GEMM (ws) | per-chunk: S=QK^T (tri,f16) -> causal softmax (wave/row) ->
// O = P@V^T (LPT-ordered) -> d_out f32.
// GEMM r10: 16 waves/block (1024 thr, 4 waves/SIMD), wave-tile 64x64
// (acc 4x4 = 64 AGPR; fits 128-reg budget for 4 waves/SIMD). BK=64,
// [2buf][2kk][256][32] LDS (128KB), 2 phases/K-tile, stage 1.5 tiles ahead,
// uniform vmcnt(4), 2 barriers/phase-step. MFMA gaps hidden by 4-way wave
// co-issue per SIMD instead of schedule micro-management.

typedef _Float16 half8 __attribute__((ext_vector_type(8)));
typedef _Float16 half4v __attribute__((ext_vector_type(4)));
typedef float floatx4 __attribute__((ext_vector_type(4)));

#define TB 16
#define TT 2048
#define TD 1024

#define BARRIER() asm volatile("s_barrier" ::: "memory")

// ---------------- convert x fp32 -> fp16 ----------------
__global__ void cvt_f32_f16(const float* __restrict__ in, _Float16* __restrict__ out, long n) {
    long i = ((long)blockIdx.x * blockDim.x + threadIdx.x) * 4;
    long stride = (long)gridDim.x * blockDim.x * 4;
    for (; i < n; i += stride) {
        float4 f = *(const float4*)(in + i);
        half4v h;
        h[0] = (_Float16)f.x; h[1] = (_Float16)f.y;
        h[2] = (_Float16)f.z; h[3] = (_Float16)f.w;
        *(half4v*)(out + i) = h;
    }
}

// ---------------- transpose + convert W [1024,1024] ----------------
__global__ void transpose_cvt_w(const float* __restrict__ in, _Float16* __restrict__ out) {
    __shared__ float tile[32][33];
    const int bx = blockIdx.x * 32, by = blockIdx.y * 32;
    const int tx = threadIdx.x, ty = threadIdx.y; // block 32x8
#pragma unroll
    for (int i = ty; i < 32; i += 8) tile[i][tx] = in[(long)(by + i) * 1024 + bx + tx];
    __syncthreads();
#pragma unroll
    for (int i = ty; i < 32; i += 8) out[(long)(bx + i) * 1024 + by + tx] = (_Float16)tile[tx][i];
}

// ---------------- 256x256 16-wave BT GEMM ----------------
// C[i,j] = sum_k A[i,k]*B[j,k]; A:[M,K] f16 (lda), B:[N,K] f16 (ldb)
// MODE 0: f16 out, plain grid.     MODE 1: f16 out, lower-tri tile grid.
// MODE 2: f32 out, 1D LPT grid (heavy ti first), K trimmed to (ti+1)*256.
// MODE 3: f16 out, plain grid, split outputs at col TD (Cout / Cout2).
__device__ __forceinline__ void gload16(const _Float16* g, _Float16* l) {
    __builtin_amdgcn_global_load_lds((const __attribute__((address_space(1))) void*)g,
                                     (__attribute__((address_space(3))) void*)l, 16, 0, 0);
}

template <int MODE>
__global__ __launch_bounds__(1024, 4) void gemm256(const _Float16* __restrict__ A,
                                                   const _Float16* __restrict__ B,
                                                   void* __restrict__ Cout,
                                                   void* __restrict__ Cout2,
                                                   int K, int lda, int ldb, int ldc,
                                                   long sAb, long sBb, long sCb,
                                                   int tilesN, int tilesM, int nb) {
    // LDS: As regions [2buf][2kk][256][32] f16 (64KB) then Bs same (64KB).
    __shared__ _Float16 lds[65536];
    const int tid = threadIdx.x, lane = tid & 63, w = tid >> 6; // w 0..15
    const int wr = w >> 2, wc = w & 3;                          // 4x4 wave grid

    int b, ti, tj;
    if (MODE == 2) {
        // LPT: raw order descending work; XCD swizzle within equal-work group
        const int grp = nb * 4;
        const int g = blockIdx.x / grp;
        ti = tilesM - 1 - g;
        int i2 = blockIdx.x - g * grp;
        const int q = grp >> 3, r = grp & 7, xcd = i2 & 7, idx = i2 >> 3;
        i2 = (xcd < r ? xcd * (q + 1) : r * (q + 1) + (xcd - r) * q) + idx;
        b = i2 >> 2; tj = i2 & 3;
    } else {
        int bx = blockIdx.x;
        const int nwg = gridDim.x, q = nwg >> 3, r = nwg & 7, xcd = bx & 7, idx = bx >> 3;
        bx = (xcd < r ? xcd * (q + 1) : r * (q + 1) + (xcd - r) * q) + idx;
        b = blockIdx.y;
        if (MODE == 1) {
            int rd = bx; ti = 0;
            while (rd > ti) { rd -= ti + 1; ++ti; }
            tj = rd;
        } else {
            ti = bx / tilesN; tj = bx % tilesN;
        }
    }
    A += (long)b * sAb;
    B += (long)b * sBb;
    const long m0 = (long)ti * 256, n0 = (long)tj * 256;
    const int nkt = (MODE == 2) ? (ti + 1) * 4 : (K >> 6);

    // staging: thread stages ONE 16B chunk per half-tile (1024 chunks = 16KB).
    const int row0 = tid >> 2;                                  // 0..255
    const int co   = (((tid & 3) ^ ((tid >> 3) & 3)) << 3);     // inverse-swizzled f16 col
    // frag read: lane wants logical chunk (lane>>4); stored at chunk ^ ((row>>1)&3)
    const int fcol = ((((lane >> 4) ^ (lane >> 1)) & 3) << 3);
    const int arow = wr * 64 + (lane & 15);
    const int brow = wc * 64 + (lane & 15);

    auto Abase = [&](int buf, int kk) { return lds + ((buf * 2 + kk) << 13); };
    auto Bbase = [&](int buf, int kk) { return lds + 32768 + ((buf * 2 + kk) << 13); };

    auto stageA = [&](int buf, int kk, int kt) {
        gload16(A + (m0 + row0) * (long)lda + (long)kt * 64 + kk * 32 + co,
                Abase(buf, kk) + (w << 9)); // wave-uniform base: w*64 chunks
    };
    auto stageB = [&](int buf, int kk, int kt) {
        gload16(B + (n0 + row0) * (long)ldb + (long)kt * 64 + kk * 32 + co,
                Bbase(buf, kk) + (w << 9));
    };
    auto ldA = [&](int buf, int kk, int m) {
        return *(const half8*)(Abase(buf, kk) + (arow + m * 16) * 32 + fcol);
    };
    auto ldB = [&](int buf, int kk, int n) {
        return *(const half8*)(Bbase(buf, kk) + (brow + n * 16) * 32 + fcol);
    };

    floatx4 acc[4][4] = {};
    half8 af[4], bf[4];

    // prologue: stage halves (0,k0) (0,k1) (1,k0) = 6 loads (1.5 tiles ahead)
    stageA(0, 0, 0); stageB(0, 0, 0);
    stageA(0, 1, 0); stageB(0, 1, 0);
    stageA(1, 0, 1); stageB(1, 0, 1);
    asm volatile("s_waitcnt vmcnt(4)" ::: "memory"); // (0,k0) landed
    BARRIER();

    for (int t = 0; t < nkt; ++t) {
        const int cur = t & 1, nxt = cur ^ 1;
        const int kt1 = (t + 1 < nkt) ? t + 1 : nkt - 1;
        const int kt2 = (t + 2 < nkt) ? t + 2 : nkt - 1;
        // ---- phase kk=0: stage (t+1,k1); read (cur,k0); MFMA; drain (t,k1) ----
        stageA(nxt, 1, kt1); stageB(nxt, 1, kt1);
#pragma unroll
        for (int nn = 0; nn < 4; ++nn) bf[nn] = ldB(cur, 0, nn);
#pragma unroll
        for (int mm = 0; mm < 4; ++mm) af[mm] = ldA(cur, 0, mm);
        __builtin_amdgcn_s_setprio(1);
#pragma unroll
        for (int mm = 0; mm < 4; ++mm)
#pragma unroll
            for (int nn = 0; nn < 4; ++nn)
                acc[mm][nn] = __builtin_amdgcn_mfma_f32_16x16x32_f16(af[mm], bf[nn], acc[mm][nn], 0, 0, 0);
        __builtin_amdgcn_s_setprio(0);
        asm volatile("s_waitcnt vmcnt(4)" ::: "memory"); // (cur,k1) ready
        BARRIER();
        // ---- phase kk=1: stage (t+2,k0); read (cur,k1); MFMA; drain (t+1,k0) ----
        stageA(cur, 0, kt2); stageB(cur, 0, kt2); // (t+2)&1 == cur
#pragma unroll
        for (int nn = 0; nn < 4; ++nn) bf[nn] = ldB(cur, 1, nn);
#pragma unroll
        for (int mm = 0; mm < 4; ++mm) af[mm] = ldA(cur, 1, mm);
        __builtin_amdgcn_s_setprio(1);
#pragma unroll
        for (int mm = 0; mm < 4; ++mm)
#pragma unroll
            for (int nn = 0; nn < 4; ++nn)
                acc[mm][nn] = __builtin_amdgcn_mfma_f32_16x16x32_f16(af[mm], bf[nn], acc[mm][nn], 0, 0, 0);
        __builtin_amdgcn_s_setprio(0);
        asm volatile("s_waitcnt vmcnt(4)" ::: "memory"); // (nxt,k0) ready
        BARRIER();
    }
    asm volatile("s_waitcnt vmcnt(0) lgkmcnt(0)" ::: "memory"); // drain DMA before exit

    // epilogue: C/D layout col=lane&15, row=(lane>>4)*4+j
    const int r4 = (lane >> 4) * 4, ccol = lane & 15;
    if (MODE != 2) {
        _Float16* C;
        long nb0 = n0;
        if (MODE == 3 && n0 >= TD) { C = (_Float16*)Cout2; nb0 = n0 - TD; }
        else                        C = (_Float16*)Cout + (long)b * sCb;
#pragma unroll
        for (int m = 0; m < 4; ++m) {
            const long rbase = m0 + wr * 64 + m * 16 + r4;
#pragma unroll
            for (int n = 0; n < 4; ++n) {
                const long cbase = nb0 + wc * 64 + n * 16 + ccol;
#pragma unroll
                for (int j = 0; j < 4; ++j)
                    C[(rbase + j) * (long)ldc + cbase] = (_Float16)acc[m][n][j];
            }
        }
    } else {
        float* C = (float*)Cout + (long)b * sCb;
#pragma unroll
        for (int m = 0; m < 4; ++m) {
            const long rbase = m0 + wr * 64 + m * 16 + r4;
#pragma unroll
            for (int n = 0; n < 4; ++n) {
                const long cbase = n0 + wc * 64 + n * 16 + ccol;
#pragma unroll
                for (int j = 0; j < 4; ++j)
                    C[(rbase + j) * (long)ldc + cbase] = acc[m][n][j];
            }
        }
    }
}

// ---------------- causal row softmax, wave-per-row, in-place f16 ----------------
__global__ __launch_bounds__(256) void softmax_rows_f16(_Float16* __restrict__ S, int T) {
    const int wv = threadIdx.x >> 6, lane = threadIdx.x & 63;
    const long row = (long)blockIdx.x * 4 + wv; // chunk-local b*T + t
    const int t = (int)(row & (T - 1));
    _Float16* s = S + row * (long)T;
    const int nstore = ((t >> 8) + 1) << 8; // cover the diagonal 256-tile for PV

    float v[4][8];
    float mx = -__builtin_inff();
#pragma unroll
    for (int c = 0; c < 4; ++c) {
        const int col0 = (c * 64 + lane) * 8;
        if (col0 <= t) {
            half8 hv = *(const half8*)(s + col0);
#pragma unroll
            for (int j = 0; j < 8; ++j) {
                v[c][j] = (col0 + j <= t) ? (float)hv[j] : -__builtin_inff();
                mx = fmaxf(mx, v[c][j]);
            }
        } else {
#pragma unroll
            for (int j = 0; j < 8; ++j) v[c][j] = -__builtin_inff();
        }
    }
#pragma unroll
    for (int o = 32; o; o >>= 1) mx = fmaxf(mx, __shfl_xor(mx, o));

    float sum = 0.f;
#pragma unroll
    for (int c = 0; c < 4; ++c)
#pragma unroll
        for (int j = 0; j < 8; ++j) {
            float p = __expf(v[c][j] - mx); // exp(-inf)=0 masks
            v[c][j] = p;
            sum += p;
        }
#pragma unroll
    for (int o = 32; o; o >>= 1) sum += __shfl_xor(sum, o);
    const float inv = 1.f / sum;

#pragma unroll
    for (int c = 0; c < 4; ++c) {
        const int col0 = (c * 64 + lane) * 8;
        if (col0 < nstore) {
            half8 o;
#pragma unroll
            for (int j = 0; j < 8; ++j) o[j] = (_Float16)(v[c][j] * inv);
            *(half8*)(s + col0) = o;
        }
    }
}

// ---------------- launch ----------------
extern "C" void kernel_launch(void* const* d_in, const int* in_sizes, int n_in,
                              void* d_out, int out_size, void* d_ws, size_t ws_size,
                              hipStream_t stream) {
    const float* x  = (const float*)d_in[0];
    const float* Wq = (const float*)d_in[1];
    const float* Wk = (const float*)d_in[2];
    const float* Wv = (const float*)d_in[3];
    float* out = (float*)d_out;

    const size_t XB = (size_t)TB * TT * TD; // 33.5M elems

    // d_out doubles as scratch: x16 lo half, K hi half (dead before PV overwrites).
    _Float16* x16 = (_Float16*)d_out;
    _Float16* Kh  = (_Float16*)d_out + XB;

    char* ws = (char*)d_ws;
    size_t off = 0;
    auto carve = [&](size_t bytes) { char* p = ws + off; off = (off + bytes + 255) & ~(size_t)255; return p; };
    _Float16* wqt = (_Float16*)carve((size_t)TD * TD * 2); // wqt & wkt contiguous:
    _Float16* wkt = (_Float16*)carve((size_t)TD * TD * 2); //   [Wq^T ; Wk^T] = B [2048,1024]
    _Float16* wvt = (_Float16*)carve((size_t)TD * TD * 2);
    _Float16* Qh  = (_Float16*)carve(XB * 2);   // [B*T][1024]
    _Float16* Vt  = (_Float16*)carve(XB * 2);   // [B][1024][2048]

    const size_t CH = (size_t)TT * TT * 2;      // 8.39 MB / batch
    int NB = 16;
    while (NB > 1 && off + (size_t)NB * CH > ws_size) NB >>= 1;
    _Float16* Sc = (_Float16*)carve((size_t)NB * CH);

    // 1. x -> f16
    cvt_f32_f16<<<2048, 256, 0, stream>>>(x, x16, (long)XB);
    // 2. W^T f16
    transpose_cvt_w<<<dim3(32, 32), dim3(32, 8), 0, stream>>>(Wq, wqt);
    transpose_cvt_w<<<dim3(32, 32), dim3(32, 8), 0, stream>>>(Wk, wkt);
    transpose_cvt_w<<<dim3(32, 32), dim3(32, 8), 0, stream>>>(Wv, wvt);

    // 3. fused [Q|K] = x @ [Wq|Wk] : M=32768 (128 tiles), N=2048 (8 tiles);
    //    epilogue routes cols <1024 -> Qh, >=1024 -> Kh (d_out hi).
    gemm256<3><<<dim3(128 * 8, 1), 1024, 0, stream>>>(x16, wqt, Qh, Kh, TD, TD, TD, TD,
                                                      0, 0, 0, 8, 128, 0);
    // 4. Vt[b] = (x[b] @ Wv)^T : M=1024 (4), N=2048 (8)
    gemm256<0><<<dim3(4 * 8, TB), 1024, 0, stream>>>(wvt, x16, Vt, nullptr, TD, TD, TD, TT,
                                                     0, (long)TT * TD, (long)TD * TT, 8, 4, 0);

    // 5. per chunk of NB batches
    for (int cb = 0; cb < TB; cb += NB) {
        // S = Q K^T, lower-tri 256-tiles (36/batch), f16
        gemm256<1><<<dim3(36, NB), 1024, 0, stream>>>(Qh + (size_t)cb * TT * TD,
                                                      Kh + (size_t)cb * TT * TD, Sc, nullptr,
                                                      TD, TD, TD, TT,
                                                      (long)TT * TD, (long)TT * TD, (long)TT * TT, 8, 8, 0);
        // causal softmax, in-place, wave-per-row (4 rows/block)
        softmax_rows_f16<<<NB * TT / 4, 256, 0, stream>>>(Sc, TT);
        // O = P @ V^T : 1D LPT grid (heavy ti first), K trimmed causally
        gemm256<2><<<dim3(NB * 32, 1), 1024, 0, stream>>>(Sc, Vt + (size_t)cb * TD * TT,
                                                          out + (size_t)cb * TT * TD, nullptr, TT,
                                                          TT, TT, TD,
                                                          (long)TT * TT, (long)TD * TT, (long)TT * TD, 4, 8, NB);
    }
}

// Round 11
// 486.452 us; speedup vs baseline: 1.0011x; 1.0011x over previous
//
#include <hip/hip_runtime.h>
#include <hip/hip_bf16.h>

// Single-head causal attention, B=16, T=2048, D=H=1024.
// cvt x->f16 (d_out lo) | transpose W | fused QK GEMM (Q->ws, K->d_out hi) |
// Vt GEMM (ws) | per-chunk: S=QK^T (tri,f16) -> causal softmax (wave/row) ->
// O = P@V^T (LPT-ordered) -> d_out f32.
// GEMM r11: depth-3 pipeline (T4). Ring-4 kk-half LDS slots [4][256][32] per
// matrix (128KB). Per half-K-step: 2 phases {stage 1 unit || ds_reads || 16
// MFMA}; un-pinned (compiler partial lgkmcnt); vmcnt(8) ONCE per half-step —
// waits only on units issued ~3 half-steps (~2000cyc) earlier, keeps 2 units
// (8 loads) always in flight. B frags read once per half-step.

typedef _Float16 half8 __attribute__((ext_vector_type(8)));
typedef _Float16 half4v __attribute__((ext_vector_type(4)));
typedef float floatx4 __attribute__((ext_vector_type(4)));

#define TB 16
#define TT 2048
#define TD 1024

#define BARRIER() asm volatile("s_barrier" ::: "memory")

// ---------------- convert x fp32 -> fp16 ----------------
__global__ void cvt_f32_f16(const float* __restrict__ in, _Float16* __restrict__ out, long n) {
    long i = ((long)blockIdx.x * blockDim.x + threadIdx.x) * 4;
    long stride = (long)gridDim.x * blockDim.x * 4;
    for (; i < n; i += stride) {
        float4 f = *(const float4*)(in + i);
        half4v h;
        h[0] = (_Float16)f.x; h[1] = (_Float16)f.y;
        h[2] = (_Float16)f.z; h[3] = (_Float16)f.w;
        *(half4v*)(out + i) = h;
    }
}

// ---------------- transpose + convert W [1024,1024] ----------------
__global__ void transpose_cvt_w(const float* __restrict__ in, _Float16* __restrict__ out) {
    __shared__ float tile[32][33];
    const int bx = blockIdx.x * 32, by = blockIdx.y * 32;
    const int tx = threadIdx.x, ty = threadIdx.y; // block 32x8
#pragma unroll
    for (int i = ty; i < 32; i += 8) tile[i][tx] = in[(long)(by + i) * 1024 + bx + tx];
    __syncthreads();
#pragma unroll
    for (int i = ty; i < 32; i += 8) out[(long)(bx + i) * 1024 + by + tx] = (_Float16)tile[tx][i];
}

// ---------------- 256x256 8-wave depth-3 BT GEMM ----------------
// C[i,j] = sum_k A[i,k]*B[j,k]; A:[M,K] f16 (lda), B:[N,K] f16 (ldb)
// MODE 0: f16 out, plain grid.     MODE 1: f16 out, lower-tri tile grid.
// MODE 2: f32 out, 1D LPT grid (heavy ti first), K trimmed to (ti+1)*256.
// MODE 3: f16 out, plain grid, split outputs at col TD (Cout / Cout2).
__device__ __forceinline__ void gload16(const _Float16* g, _Float16* l) {
    __builtin_amdgcn_global_load_lds((const __attribute__((address_space(1))) void*)g,
                                     (__attribute__((address_space(3))) void*)l, 16, 0, 0);
}

template <int MODE>
__global__ __launch_bounds__(512, 2) void gemm256(const _Float16* __restrict__ A,
                                                  const _Float16* __restrict__ B,
                                                  void* __restrict__ Cout,
                                                  void* __restrict__ Cout2,
                                                  int K, int lda, int ldb, int ldc,
                                                  long sAb, long sBb, long sCb,
                                                  int tilesN, int tilesM, int nb) {
    // LDS: A ring [4][256][32] f16 (64KB) then B ring same (64KB).
    __shared__ _Float16 lds[65536];
    const int tid = threadIdx.x, lane = tid & 63, w = tid >> 6; // 8 waves
    const int wr = w >> 2, wc = w & 3;                          // 2M x 4N wave grid

    int b, ti, tj;
    if (MODE == 2) {
        // LPT: raw order descending work; XCD swizzle within equal-work group
        const int grp = nb * 4;
        const int g = blockIdx.x / grp;
        ti = tilesM - 1 - g;
        int i2 = blockIdx.x - g * grp;
        const int q = grp >> 3, r = grp & 7, xcd = i2 & 7, idx = i2 >> 3;
        i2 = (xcd < r ? xcd * (q + 1) : r * (q + 1) + (xcd - r) * q) + idx;
        b = i2 >> 2; tj = i2 & 3;
    } else {
        int bx = blockIdx.x;
        const int nwg = gridDim.x, q = nwg >> 3, r = nwg & 7, xcd = bx & 7, idx = bx >> 3;
        bx = (xcd < r ? xcd * (q + 1) : r * (q + 1) + (xcd - r) * q) + idx;
        b = blockIdx.y;
        if (MODE == 1) {
            int rd = bx; ti = 0;
            while (rd > ti) { rd -= ti + 1; ++ti; }
            tj = rd;
        } else {
            ti = bx / tilesN; tj = bx % tilesN;
        }
    }
    A += (long)b * sAb;
    B += (long)b * sBb;
    const long m0 = (long)ti * 256, n0 = (long)tj * 256;
    const int nh = (MODE == 2) ? (ti + 1) * 8 : (K >> 5); // half-K-steps (32 k each)

    // staging: thread stages chunk tid and tid+512 per (matrix, unit).
    const int row0 = tid >> 2;                                  // 0..127 (+128 for 2nd load)
    const int co   = (((tid & 3) ^ ((tid >> 3) & 3)) << 3);     // inverse-swizzled f16 col
    // frag read: lane wants logical chunk (lane>>4); stored at chunk ^ ((row>>1)&3)
    const int fcol = ((((lane >> 4) ^ (lane >> 1)) & 3) << 3);
    const int arow = wr * 128 + (lane & 15);
    const int brow = wc * 64 + (lane & 15);

    auto Abase = [&](int slot) { return lds + (slot << 13); };
    auto Bbase = [&](int slot) { return lds + 32768 + (slot << 13); };

    auto stageA = [&](int slot, int kh) {
        const long kb = (long)kh * 32 + co;
        _Float16* d = Abase(slot) + (w << 9); // wave-uniform base: w*64 chunks
        gload16(A + (m0 + row0) * (long)lda + kb, d);
        gload16(A + (m0 + row0 + 128) * (long)lda + kb, d + 4096);
    };
    auto stageB = [&](int slot, int kh) {
        const long kb = (long)kh * 32 + co;
        _Float16* d = Bbase(slot) + (w << 9);
        gload16(B + (n0 + row0) * (long)ldb + kb, d);
        gload16(B + (n0 + row0 + 128) * (long)ldb + kb, d + 4096);
    };
    auto ldA = [&](int slot, int m) {
        return *(const half8*)(Abase(slot) + (arow + m * 16) * 32 + fcol);
    };
    auto ldB = [&](int slot, int n) {
        return *(const half8*)(Bbase(slot) + (brow + n * 16) * 32 + fcol);
    };

    floatx4 acc[8][4] = {};
    half8 af[4], bf[4];

#define MFMA16(MH)                                                                     \
    _Pragma("unroll") for (int mm = 0; mm < 4; ++mm)                                   \
    _Pragma("unroll") for (int nn = 0; nn < 4; ++nn)                                   \
        acc[(MH)*4 + mm][nn] =                                                         \
            __builtin_amdgcn_mfma_f32_16x16x32_f16(af[mm], bf[nn], acc[(MH)*4 + mm][nn], 0, 0, 0);

    // prologue: stage units 0,1,2 (12 gloads, depth 3)
    {
        const int k1 = (1 < nh) ? 1 : nh - 1, k2 = (2 < nh) ? 2 : nh - 1;
        stageA(0, 0); stageB(0, 0);
        stageA(1, k1); stageB(1, k1);
        stageA(2, k2); stageB(2, k2);
    }
    asm volatile("s_waitcnt vmcnt(8)" ::: "memory"); // unit 0 (A+B) landed
    BARRIER();

    for (int h = 0; h < nh; ++h) {
        const int s = h & 3, s3 = (h + 3) & 3;               // s3 provably dead slot
        const int kh3 = (h + 3 < nh) ? h + 3 : nh - 1;       // clamped tail (count-only)
        // ---- phase 0 (mh=0): stage A-unit(h+3) || read B+A || MFMA ----
        stageA(s3, kh3);
#pragma unroll
        for (int nn = 0; nn < 4; ++nn) bf[nn] = ldB(s, nn);
#pragma unroll
        for (int mm = 0; mm < 4; ++mm) af[mm] = ldA(s, mm);
        __builtin_amdgcn_s_setprio(1);
        MFMA16(0)
        __builtin_amdgcn_s_setprio(0);
        BARRIER();
        // ---- phase 1 (mh=1): stage B-unit(h+3) || read A || MFMA ----
        stageB(s3, kh3);
#pragma unroll
        for (int mm = 0; mm < 4; ++mm) af[mm] = ldA(s, mm + 4);
        __builtin_amdgcn_s_setprio(1);
        MFMA16(1)
        __builtin_amdgcn_s_setprio(0);
        // forces unit h+1 landed; keeps units h+2,h+3 (8 loads) in flight
        asm volatile("s_waitcnt vmcnt(8)" ::: "memory");
        BARRIER();
    }
#undef MFMA16
    asm volatile("s_waitcnt vmcnt(0) lgkmcnt(0)" ::: "memory"); // drain DMA before exit

    // epilogue: C/D layout col=lane&15, row=(lane>>4)*4+j
    const int r4 = (lane >> 4) * 4, ccol = lane & 15;
    if (MODE != 2) {
        _Float16* C;
        long nb0 = n0;
        if (MODE == 3 && n0 >= TD) { C = (_Float16*)Cout2; nb0 = n0 - TD; }
        else                        C = (_Float16*)Cout + (long)b * sCb;
#pragma unroll
        for (int m = 0; m < 8; ++m) {
            const long rbase = m0 + wr * 128 + m * 16 + r4;
#pragma unroll
            for (int n = 0; n < 4; ++n) {
                const long cbase = nb0 + wc * 64 + n * 16 + ccol;
#pragma unroll
                for (int j = 0; j < 4; ++j)
                    C[(rbase + j) * (long)ldc + cbase] = (_Float16)acc[m][n][j];
            }
        }
    } else {
        float* C = (float*)Cout + (long)b * sCb;
#pragma unroll
        for (int m = 0; m < 8; ++m) {
            const long rbase = m0 + wr * 128 + m * 16 + r4;
#pragma unroll
            for (int n = 0; n < 4; ++n) {
                const long cbase = n0 + wc * 64 + n * 16 + ccol;
#pragma unroll
                for (int j = 0; j < 4; ++j)
                    C[(rbase + j) * (long)ldc + cbase] = acc[m][n][j];
            }
        }
    }
}

// ---------------- causal row softmax, wave-per-row, in-place f16 ----------------
__global__ __launch_bounds__(256) void softmax_rows_f16(_Float16* __restrict__ S, int T) {
    const int wv = threadIdx.x >> 6, lane = threadIdx.x & 63;
    const long row = (long)blockIdx.x * 4 + wv; // chunk-local b*T + t
    const int t = (int)(row & (T - 1));
    _Float16* s = S + row * (long)T;
    const int nstore = ((t >> 8) + 1) << 8; // cover the diagonal 256-tile for PV

    float v[4][8];
    float mx = -__builtin_inff();
#pragma unroll
    for (int c = 0; c < 4; ++c) {
        const int col0 = (c * 64 + lane) * 8;
        if (col0 <= t) {
            half8 hv = *(const half8*)(s + col0);
#pragma unroll
            for (int j = 0; j < 8; ++j) {
                v[c][j] = (col0 + j <= t) ? (float)hv[j] : -__builtin_inff();
                mx = fmaxf(mx, v[c][j]);
            }
        } else {
#pragma unroll
            for (int j = 0; j < 8; ++j) v[c][j] = -__builtin_inff();
        }
    }
#pragma unroll
    for (int o = 32; o; o >>= 1) mx = fmaxf(mx, __shfl_xor(mx, o));

    float sum = 0.f;
#pragma unroll
    for (int c = 0; c < 4; ++c)
#pragma unroll
        for (int j = 0; j < 8; ++j) {
            float p = __expf(v[c][j] - mx); // exp(-inf)=0 masks
            v[c][j] = p;
            sum += p;
        }
#pragma unroll
    for (int o = 32; o; o >>= 1) sum += __shfl_xor(sum, o);
    const float inv = 1.f / sum;

#pragma unroll
    for (int c = 0; c < 4; ++c) {
        const int col0 = (c * 64 + lane) * 8;
        if (col0 < nstore) {
            half8 o;
#pragma unroll
            for (int j = 0; j < 8; ++j) o[j] = (_Float16)(v[c][j] * inv);
            *(half8*)(s + col0) = o;
        }
    }
}

// ---------------- launch ----------------
extern "C" void kernel_launch(void* const* d_in, const int* in_sizes, int n_in,
                              void* d_out, int out_size, void* d_ws, size_t ws_size,
                              hipStream_t stream) {
    const float* x  = (const float*)d_in[0];
    const float* Wq = (const float*)d_in[1];
    const float* Wk = (const float*)d_in[2];
    const float* Wv = (const float*)d_in[3];
    float* out = (float*)d_out;

    const size_t XB = (size_t)TB * TT * TD; // 33.5M elems

    // d_out doubles as scratch: x16 lo half, K hi half (dead before PV overwrites).
    _Float16* x16 = (_Float16*)d_out;
    _Float16* Kh  = (_Float16*)d_out + XB;

    char* ws = (char*)d_ws;
    size_t off = 0;
    auto carve = [&](size_t bytes) { char* p = ws + off; off = (off + bytes + 255) & ~(size_t)255; return p; };
    _Float16* wqt = (_Float16*)carve((size_t)TD * TD * 2); // wqt & wkt contiguous:
    _Float16* wkt = (_Float16*)carve((size_t)TD * TD * 2); //   [Wq^T ; Wk^T] = B [2048,1024]
    _Float16* wvt = (_Float16*)carve((size_t)TD * TD * 2);
    _Float16* Qh  = (_Float16*)carve(XB * 2);   // [B*T][1024]
    _Float16* Vt  = (_Float16*)carve(XB * 2);   // [B][1024][2048]

    const size_t CH = (size_t)TT * TT * 2;      // 8.39 MB / batch
    int NB = 16;
    while (NB > 1 && off + (size_t)NB * CH > ws_size) NB >>= 1;
    _Float16* Sc = (_Float16*)carve((size_t)NB * CH);

    // 1. x -> f16
    cvt_f32_f16<<<2048, 256, 0, stream>>>(x, x16, (long)XB);
    // 2. W^T f16
    transpose_cvt_w<<<dim3(32, 32), dim3(32, 8), 0, stream>>>(Wq, wqt);
    transpose_cvt_w<<<dim3(32, 32), dim3(32, 8), 0, stream>>>(Wk, wkt);
    transpose_cvt_w<<<dim3(32, 32), dim3(32, 8), 0, stream>>>(Wv, wvt);

    // 3. fused [Q|K] = x @ [Wq|Wk] : M=32768 (128 tiles), N=2048 (8 tiles);
    //    epilogue routes cols <1024 -> Qh, >=1024 -> Kh (d_out hi).
    gemm256<3><<<dim3(128 * 8, 1), 512, 0, stream>>>(x16, wqt, Qh, Kh, TD, TD, TD, TD,
                                                     0, 0, 0, 8, 128, 0);
    // 4. Vt[b] = (x[b] @ Wv)^T : M=1024 (4), N=2048 (8)
    gemm256<0><<<dim3(4 * 8, TB), 512, 0, stream>>>(wvt, x16, Vt, nullptr, TD, TD, TD, TT,
                                                    0, (long)TT * TD, (long)TD * TT, 8, 4, 0);

    // 5. per chunk of NB batches
    for (int cb = 0; cb < TB; cb += NB) {
        // S = Q K^T, lower-tri 256-tiles (36/batch), f16
        gemm256<1><<<dim3(36, NB), 512, 0, stream>>>(Qh + (size_t)cb * TT * TD,
                                                     Kh + (size_t)cb * TT * TD, Sc, nullptr,
                                                     TD, TD, TD, TT,
                                                     (long)TT * TD, (long)TT * TD, (long)TT * TT, 8, 8, 0);
        // causal softmax, in-place, wave-per-row (4 rows/block)
        softmax_rows_f16<<<NB * TT / 4, 256, 0, stream>>>(Sc, TT);
        // O = P @ V^T : 1D LPT grid (heavy ti first), K trimmed causally
        gemm256<2><<<dim3(NB * 32, 1), 512, 0, stream>>>(Sc, Vt + (size_t)cb * TD * TT,
                                                         out + (size_t)cb * TT * TD, nullptr, TT,
                                                         TT, TT, TD,
                                                         (long)TT * TT, (long)TD * TT, (long)TT * TD, 4, 8, NB);
    }
}

// Round 12
// 470.686 us; speedup vs baseline: 1.0346x; 1.0335x over previous
//
#include <hip/hip_runtime.h>
#include <hip/hip_bf16.h>

// Single-head causal attention, B=16, T=2048, D=H=1024.
// cvt x->f16 (d_out lo) | transpose W | fused QK GEMM (Q->ws, K->d_out hi) |
// Vt GEMM (ws) | per-chunk: S=QK^T (tri,f16) -> causal softmax (wave/row) ->
// O = P@V^T (LPT-ordered) -> d_out f32.
// GEMM r12 = r7 base + (a) sched_group_barrier interleave [2 MFMA,1 ds_read]
// per phase so ds_reads issue DURING the MFMA burst (defeats in-order-issue
// pile-up behind matrix-pipe backpressure), (b) K-loop unroll 2 -> compile-
// time buf indices -> immediate-offset ds_reads, less VALU.

typedef _Float16 half8 __attribute__((ext_vector_type(8)));
typedef _Float16 half4v __attribute__((ext_vector_type(4)));
typedef float floatx4 __attribute__((ext_vector_type(4)));

#define TB 16
#define TT 2048
#define TD 1024

#define BARRIER() asm volatile("s_barrier" ::: "memory")
#define SGB(mask, n) __builtin_amdgcn_sched_group_barrier((mask), (n), 0)
// masks: MFMA=0x8, VMEM=0x10, DS_READ=0x100

// ---------------- convert x fp32 -> fp16 ----------------
__global__ void cvt_f32_f16(const float* __restrict__ in, _Float16* __restrict__ out, long n) {
    long i = ((long)blockIdx.x * blockDim.x + threadIdx.x) * 4;
    long stride = (long)gridDim.x * blockDim.x * 4;
    for (; i < n; i += stride) {
        float4 f = *(const float4*)(in + i);
        half4v h;
        h[0] = (_Float16)f.x; h[1] = (_Float16)f.y;
        h[2] = (_Float16)f.z; h[3] = (_Float16)f.w;
        *(half4v*)(out + i) = h;
    }
}

// ---------------- transpose + convert W [1024,1024] ----------------
__global__ void transpose_cvt_w(const float* __restrict__ in, _Float16* __restrict__ out) {
    __shared__ float tile[32][33];
    const int bx = blockIdx.x * 32, by = blockIdx.y * 32;
    const int tx = threadIdx.x, ty = threadIdx.y; // block 32x8
#pragma unroll
    for (int i = ty; i < 32; i += 8) tile[i][tx] = in[(long)(by + i) * 1024 + bx + tx];
    __syncthreads();
#pragma unroll
    for (int i = ty; i < 32; i += 8) out[(long)(bx + i) * 1024 + by + tx] = (_Float16)tile[tx][i];
}

// ---------------- 256x256 8-wave pipelined BT GEMM ----------------
// C[i,j] = sum_k A[i,k]*B[j,k]; A:[M,K] f16 (lda), B:[N,K] f16 (ldb)
// MODE 0: f16 out, plain grid.     MODE 1: f16 out, lower-tri tile grid.
// MODE 2: f32 out, 1D LPT grid (heavy ti first), K trimmed to (ti+1)*256.
// MODE 3: f16 out, plain grid, split outputs at col TD (Cout / Cout2).
__device__ __forceinline__ void gload16(const _Float16* g, _Float16* l) {
    __builtin_amdgcn_global_load_lds((const __attribute__((address_space(1))) void*)g,
                                     (__attribute__((address_space(3))) void*)l, 16, 0, 0);
}

template <int MODE>
__global__ __launch_bounds__(512, 2) void gemm256(const _Float16* __restrict__ A,
                                                  const _Float16* __restrict__ B,
                                                  void* __restrict__ Cout,
                                                  void* __restrict__ Cout2,
                                                  int K, int lda, int ldb, int ldc,
                                                  long sAb, long sBb, long sCb,
                                                  int tilesN, int tilesM, int nb) {
    // LDS: As regions [2buf][2kk][256][32] f16 (64KB) then Bs same (64KB).
    __shared__ _Float16 lds[65536];
    const int tid = threadIdx.x, lane = tid & 63, w = tid >> 6;
    const int wr = w >> 2, wc = w & 3;

    int b, ti, tj;
    if (MODE == 2) {
        // LPT: raw order descending work; XCD swizzle within equal-work group
        const int grp = nb * 4;
        const int g = blockIdx.x / grp;
        ti = tilesM - 1 - g;
        int i2 = blockIdx.x - g * grp;
        const int q = grp >> 3, r = grp & 7, xcd = i2 & 7, idx = i2 >> 3;
        i2 = (xcd < r ? xcd * (q + 1) : r * (q + 1) + (xcd - r) * q) + idx;
        b = i2 >> 2; tj = i2 & 3;
    } else {
        int bx = blockIdx.x;
        const int nwg = gridDim.x, q = nwg >> 3, r = nwg & 7, xcd = bx & 7, idx = bx >> 3;
        bx = (xcd < r ? xcd * (q + 1) : r * (q + 1) + (xcd - r) * q) + idx;
        b = blockIdx.y;
        if (MODE == 1) {
            int rd = bx; ti = 0;
            while (rd > ti) { rd -= ti + 1; ++ti; }
            tj = rd;
        } else {
            ti = bx / tilesN; tj = bx % tilesN;
        }
    }
    A += (long)b * sAb;
    B += (long)b * sBb;
    const long m0 = (long)ti * 256, n0 = (long)tj * 256;
    const int nkt = (MODE == 2) ? (ti + 1) * 4 : (K >> 6); // always even

    // staging: thread stages chunk tid and tid+512 per (matrix, region).
    const int row0 = tid >> 2;                                  // 0..127 (+128 for 2nd load)
    const int co   = (((tid & 3) ^ ((tid >> 3) & 3)) << 3);     // inverse-swizzled f16 col
    // frag read: lane wants logical chunk (lane>>4); stored at chunk ^ ((row>>1)&3)
    const int fcol = ((((lane >> 4) ^ (lane >> 1)) & 3) << 3);
    const int arow = wr * 128 + (lane & 15);
    const int brow = wc * 64 + (lane & 15);

    auto Abase = [&](int buf, int kk) { return lds + ((buf * 2 + kk) << 13); };
    auto Bbase = [&](int buf, int kk) { return lds + 32768 + ((buf * 2 + kk) << 13); };

    auto stageA = [&](int buf, int kk, int kt) {
        const long kb = (long)kt * 64 + kk * 32 + co;
        _Float16* d = Abase(buf, kk) + (w << 9); // wave-uniform base: w*64 chunks
        gload16(A + (m0 + row0) * (long)lda + kb, d);
        gload16(A + (m0 + row0 + 128) * (long)lda + kb, d + 4096);
    };
    auto stageB = [&](int buf, int kk, int kt) {
        const long kb = (long)kt * 64 + kk * 32 + co;
        _Float16* d = Bbase(buf, kk) + (w << 9);
        gload16(B + (n0 + row0) * (long)ldb + kb, d);
        gload16(B + (n0 + row0 + 128) * (long)ldb + kb, d + 4096);
    };
    auto ldA = [&](int buf, int kk, int m) {
        return *(const half8*)(Abase(buf, kk) + (arow + m * 16) * 32 + fcol);
    };
    auto ldB = [&](int buf, int kk, int n) {
        return *(const half8*)(Bbase(buf, kk) + (brow + n * 16) * 32 + fcol);
    };

    floatx4 acc[8][4] = {};
    half8 afE[4], afO[4], bfE[4], bfO[4];

#define MFMA_Q(MH, BF, AF)                                                             \
    __builtin_amdgcn_s_setprio(1);                                                     \
    _Pragma("unroll") for (int mm = 0; mm < 4; ++mm)                                   \
    _Pragma("unroll") for (int nn = 0; nn < 4; ++nn)                                   \
        acc[(MH)*4 + mm][nn] =                                                         \
            __builtin_amdgcn_mfma_f32_16x16x32_f16(AF[mm], BF[nn], acc[(MH)*4 + mm][nn], 0, 0, 0); \
    __builtin_amdgcn_s_setprio(0);

    // interleave directives: stages first, then (MFMA x k, 1 ds_read) groups
#define ILV4()                                                                         \
    SGB(0x10, 2);                                                                      \
    _Pragma("unroll") for (int s_ = 0; s_ < 4; ++s_) { SGB(0x8, 3); SGB(0x100, 1); }   \
    SGB(0x8, 4);
#define ILV8()                                                                         \
    SGB(0x10, 2);                                                                      \
    _Pragma("unroll") for (int s_ = 0; s_ < 8; ++s_) { SGB(0x8, 2); SGB(0x100, 1); }

    // prologue: stage H(0,0) H(0,1) H(1,0) = 12 loads, 1.5 K-tiles ahead
    {
        const int k1 = (1 < nkt) ? 1 : nkt - 1;
        stageA(0, 0, 0); stageB(0, 0, 0);
        stageA(0, 1, 0); stageB(0, 1, 0);
        stageA(1, 0, k1); stageB(1, 0, k1);
    }
    asm volatile("s_waitcnt vmcnt(8)" ::: "memory"); // H(0,0) landed (this wave)
    BARRIER();                                       // publish H(0,0)
#pragma unroll
    for (int nn = 0; nn < 4; ++nn) bfE[nn] = ldB(0, 0, nn);
#pragma unroll
    for (int mm = 0; mm < 4; ++mm) afE[mm] = ldA(0, 0, mm);

#pragma unroll 2
    for (int t = 0; t < nkt; ++t) {
        const int cur = t & 1, nxt = cur ^ 1;
        const int kt1 = (t + 1 < nkt) ? t + 1 : nkt - 1;
        const int kt2 = (t + 2 < nkt) ? t + 2 : nkt - 1;
        // ---- P0: MFMA q0(cur,kk0) || reads afO<-A(cur,0,hi) ; stage A(t+1,1) ----
        MFMA_Q(0, bfE, afE)
#pragma unroll
        for (int mm = 0; mm < 4; ++mm) afO[mm] = ldA(cur, 0, mm + 4);
        stageA(nxt, 1, kt1);
        ILV4()
        asm volatile("s_waitcnt vmcnt(6)" ::: "memory"); // H(t,1) landed
        BARRIER();                                       // publish H(t,1)
        // ---- P1: MFMA q1(cur,kk0) || reads bfO,afE<-(cur,1) ; stage B(t+1,1) ----
        MFMA_Q(1, bfE, afO)
#pragma unroll
        for (int nn = 0; nn < 4; ++nn) bfO[nn] = ldB(cur, 1, nn);
#pragma unroll
        for (int mm = 0; mm < 4; ++mm) afE[mm] = ldA(cur, 1, mm);
        stageB(nxt, 1, kt1);
        ILV8()
        BARRIER();
        // ---- P2: MFMA q0(cur,kk1) || reads afO<-A(cur,1,hi) ; stage A(t+2,0) ----
        MFMA_Q(0, bfO, afE)
#pragma unroll
        for (int mm = 0; mm < 4; ++mm) afO[mm] = ldA(cur, 1, mm + 4);
        stageA(cur, 0, kt2); // (t+2)&1 == t&1
        ILV4()
        asm volatile("s_waitcnt vmcnt(6)" ::: "memory"); // H(t+1,0) landed
        BARRIER();                                       // publish H(t+1,0)
        // ---- P3: MFMA q1(cur,kk1) || reads bfE,afE<-(nxt,0) ; stage B(t+2,0) ----
        MFMA_Q(1, bfO, afO)
#pragma unroll
        for (int nn = 0; nn < 4; ++nn) bfE[nn] = ldB(nxt, 0, nn);
#pragma unroll
        for (int mm = 0; mm < 4; ++mm) afE[mm] = ldA(nxt, 0, mm);
        stageB(cur, 0, kt2);
        ILV8()
        BARRIER();
    }
#undef MFMA_Q
#undef ILV4
#undef ILV8
    asm volatile("s_waitcnt vmcnt(0) lgkmcnt(0)" ::: "memory"); // drain DMA before exit

    // epilogue: C/D layout col=lane&15, row=(lane>>4)*4+j
    const int r4 = (lane >> 4) * 4, ccol = lane & 15;
    if (MODE != 2) {
        _Float16* C;
        long nb0 = n0;
        if (MODE == 3 && n0 >= TD) { C = (_Float16*)Cout2; nb0 = n0 - TD; }
        else                        C = (_Float16*)Cout + (long)b * sCb;
#pragma unroll
        for (int m = 0; m < 8; ++m) {
            const long rbase = m0 + wr * 128 + m * 16 + r4;
#pragma unroll
            for (int n = 0; n < 4; ++n) {
                const long cbase = nb0 + wc * 64 + n * 16 + ccol;
#pragma unroll
                for (int j = 0; j < 4; ++j)
                    C[(rbase + j) * (long)ldc + cbase] = (_Float16)acc[m][n][j];
            }
        }
    } else {
        float* C = (float*)Cout + (long)b * sCb;
#pragma unroll
        for (int m = 0; m < 8; ++m) {
            const long rbase = m0 + wr * 128 + m * 16 + r4;
#pragma unroll
            for (int n = 0; n < 4; ++n) {
                const long cbase = n0 + wc * 64 + n * 16 + ccol;
#pragma unroll
                for (int j = 0; j < 4; ++j)
                    C[(rbase + j) * (long)ldc + cbase] = acc[m][n][j];
            }
        }
    }
}

// ---------------- causal row softmax, wave-per-row, in-place f16 ----------------
__global__ __launch_bounds__(256) void softmax_rows_f16(_Float16* __restrict__ S, int T) {
    const int wv = threadIdx.x >> 6, lane = threadIdx.x & 63;
    const long row = (long)blockIdx.x * 4 + wv; // chunk-local b*T + t
    const int t = (int)(row & (T - 1));
    _Float16* s = S + row * (long)T;
    const int nstore = ((t >> 8) + 1) << 8; // cover the diagonal 256-tile for PV

    float v[4][8];
    float mx = -__builtin_inff();
#pragma unroll
    for (int c = 0; c < 4; ++c) {
        const int col0 = (c * 64 + lane) * 8;
        if (col0 <= t) {
            half8 hv = *(const half8*)(s + col0);
#pragma unroll
            for (int j = 0; j < 8; ++j) {
                v[c][j] = (col0 + j <= t) ? (float)hv[j] : -__builtin_inff();
                mx = fmaxf(mx, v[c][j]);
            }
        } else {
#pragma unroll
            for (int j = 0; j < 8; ++j) v[c][j] = -__builtin_inff();
        }
    }
#pragma unroll
    for (int o = 32; o; o >>= 1) mx = fmaxf(mx, __shfl_xor(mx, o));

    float sum = 0.f;
#pragma unroll
    for (int c = 0; c < 4; ++c)
#pragma unroll
        for (int j = 0; j < 8; ++j) {
            float p = __expf(v[c][j] - mx); // exp(-inf)=0 masks
            v[c][j] = p;
            sum += p;
        }
#pragma unroll
    for (int o = 32; o; o >>= 1) sum += __shfl_xor(sum, o);
    const float inv = 1.f / sum;

#pragma unroll
    for (int c = 0; c < 4; ++c) {
        const int col0 = (c * 64 + lane) * 8;
        if (col0 < nstore) {
            half8 o;
#pragma unroll
            for (int j = 0; j < 8; ++j) o[j] = (_Float16)(v[c][j] * inv);
            *(half8*)(s + col0) = o;
        }
    }
}

// ---------------- launch ----------------
extern "C" void kernel_launch(void* const* d_in, const int* in_sizes, int n_in,
                              void* d_out, int out_size, void* d_ws, size_t ws_size,
                              hipStream_t stream) {
    const float* x  = (const float*)d_in[0];
    const float* Wq = (const float*)d_in[1];
    const float* Wk = (const float*)d_in[2];
    const float* Wv = (const float*)d_in[3];
    float* out = (float*)d_out;

    const size_t XB = (size_t)TB * TT * TD; // 33.5M elems

    // d_out doubles as scratch: x16 lo half, K hi half (dead before PV overwrites).
    _Float16* x16 = (_Float16*)d_out;
    _Float16* Kh  = (_Float16*)d_out + XB;

    char* ws = (char*)d_ws;
    size_t off = 0;
    auto carve = [&](size_t bytes) { char* p = ws + off; off = (off + bytes + 255) & ~(size_t)255; return p; };
    _Float16* wqt = (_Float16*)carve((size_t)TD * TD * 2); // wqt & wkt contiguous:
    _Float16* wkt = (_Float16*)carve((size_t)TD * TD * 2); //   [Wq^T ; Wk^T] = B [2048,1024]
    _Float16* wvt = (_Float16*)carve((size_t)TD * TD * 2);
    _Float16* Qh  = (_Float16*)carve(XB * 2);   // [B*T][1024]
    _Float16* Vt  = (_Float16*)carve(XB * 2);   // [B][1024][2048]

    const size_t CH = (size_t)TT * TT * 2;      // 8.39 MB / batch
    int NB = 16;
    while (NB > 1 && off + (size_t)NB * CH > ws_size) NB >>= 1;
    _Float16* Sc = (_Float16*)carve((size_t)NB * CH);

    // 1. x -> f16
    cvt_f32_f16<<<2048, 256, 0, stream>>>(x, x16, (long)XB);
    // 2. W^T f16
    transpose_cvt_w<<<dim3(32, 32), dim3(32, 8), 0, stream>>>(Wq, wqt);
    transpose_cvt_w<<<dim3(32, 32), dim3(32, 8), 0, stream>>>(Wk, wkt);
    transpose_cvt_w<<<dim3(32, 32), dim3(32, 8), 0, stream>>>(Wv, wvt);

    // 3. fused [Q|K] = x @ [Wq|Wk] : M=32768 (128 tiles), N=2048 (8 tiles);
    //    epilogue routes cols <1024 -> Qh, >=1024 -> Kh (d_out hi).
    gemm256<3><<<dim3(128 * 8, 1), 512, 0, stream>>>(x16, wqt, Qh, Kh, TD, TD, TD, TD,
                                                     0, 0, 0, 8, 128, 0);
    // 4. Vt[b] = (x[b] @ Wv)^T : M=1024 (4), N=2048 (8)
    gemm256<0><<<dim3(4 * 8, TB), 512, 0, stream>>>(wvt, x16, Vt, nullptr, TD, TD, TD, TT,
                                                    0, (long)TT * TD, (long)TD * TT, 8, 4, 0);

    // 5. per chunk of NB batches
    for (int cb = 0; cb < TB; cb += NB) {
        // S = Q K^T, lower-tri 256-tiles (36/batch), f16
        gemm256<1><<<dim3(36, NB), 512, 0, stream>>>(Qh + (size_t)cb * TT * TD,
                                                     Kh + (size_t)cb * TT * TD, Sc, nullptr,
                                                     TD, TD, TD, TT,
                                                     (long)TT * TD, (long)TT * TD, (long)TT * TT, 8, 8, 0);
        // causal softmax, in-place, wave-per-row (4 rows/block)
        softmax_rows_f16<<<NB * TT / 4, 256, 0, stream>>>(Sc, TT);
        // O = P @ V^T : 1D LPT grid (heavy ti first), K trimmed causally
        gemm256<2><<<dim3(NB * 32, 1), 512, 0, stream>>>(Sc, Vt + (size_t)cb * TD * TT,
                                                         out + (size_t)cb * TT * TD, nullptr, TT,
                                                         TT, TT, TD,
                                                         (long)TT * TT, (long)TD * TT, (long)TT * TD, 4, 8, NB);
    }
}